// Round 7
// baseline (215.341 us; speedup 1.0000x reference)
//
#include <hip/hip_runtime.h>
#include <stdint.h>

// B=128, K_fc=32 -> 4096 rows, F=2048, K_LIST={64,128,256,512}, TAU=1, EPS=1e-20.
// Output = M_hard exactly (straight-through term is numerically zero forward).
//
// R7: one wave per row, 64-thread blocks, ZERO real barriers (single-wave
// workgroup -> __syncthreads folds to waitcnt). Wave-private 12-bit radix
// histogram (packed u16, +1/32 padding => conflict-free scan reads), desc32
// key cache in LDS, shfl-based wave scan, gated bin-find, all-pairs on the
// tiny threshold bin (cand aliases dead hist). 9 independent waves/CU mix
// load/VALU/store phases freely instead of marching in barrier lockstep.

#define F_DIM  2048
#define KSB    4
#define CAP    512
#define NCHUNK 8     // 8 chunks x 64 lanes x 4 elems = 2048

typedef float f32x4 __attribute__((ext_vector_type(4)));

// Monotonic descending key: kd(a) < kd(b)  <=>  a > b (total order on f32)
__device__ __forceinline__ uint32_t f32_desc_key(float x) {
    uint32_t u = __float_as_uint(x);
    uint32_t ka = (u & 0x80000000u) ? ~u : (u | 0x80000000u);
    return ~ka;
}

__global__ __launch_bounds__(64)
void hsb_kernel(const float* __restrict__ scores,
                const float* __restrict__ uin,
                float* __restrict__ out) {
    const int row = blockIdx.x;
    const int L   = threadIdx.x;          // lane 0..63 (one wave per block)

    __shared__ uint32_t keyCache[2048];   // desc32 per element (8 KB)
    __shared__ uint32_t hist[2112];       // 4096 u16 bins packed + 1 pad word/32
    uint32_t (*cand)[CAP] = (uint32_t (*)[CAP])hist;  // alias: hist dead after find
    __shared__ uint32_t selScr[KSB];      // (bin<<12) | rem
    __shared__ uint32_t selCnt[KSB];
    __shared__ uint32_t selThr[KSB];      // packed31 threshold within bin

    const float4* s4 = (const float4*)(scores + row * F_DIM);
    const float4* u4 = (const float4*)(uin    + row * F_DIM);

    // ---- issue all global loads up front (16 KB/wave in flight) ----
    float4 sv[NCHUNK], uv[NCHUNK];
    #pragma unroll
    for (int c = 0; c < NCHUNK; ++c) { sv[c] = s4[64 * c + L]; uv[c] = u4[64 * c + L]; }

    // ---- zero hist (2112 words) while loads are in flight ----
    {
        uint4 z = {0u, 0u, 0u, 0u};
        #pragma unroll
        for (int i = 0; i < 8; ++i) ((uint4*)hist)[64 * i + L] = z;   // 2048 words
        if (L < 16) ((uint4*)hist)[512 + L] = z;                      // pad tail
    }
    if (L < KSB) selCnt[L] = 0;
    __syncthreads();   // single wave: compiles to waitcnt only

    // ---- keys + 12-bit histogram; stash desc32 in keyCache ----
    #pragma unroll
    for (int c = 0; c < NCHUNK; ++c) {
        float ss[4] = {sv[c].x, sv[c].y, sv[c].z, sv[c].w};
        float uu[4] = {uv[c].x, uv[c].y, uv[c].z, uv[c].w};
        uint32_t d32[4];
        #pragma unroll
        for (int j = 0; j < 4; ++j) {
            float inner = -logf(uu[j] + 1e-20f);   // byte-identical reference math
            float g     = -logf(inner + 1e-20f);
            d32[j] = f32_desc_key(ss[j] + g);
        }
        *(uint4*)&keyCache[256 * c + 4 * L] = *(uint4*)d32;   // b128, conflict-free
        #pragma unroll
        for (int j = 0; j < 4; ++j) {
            uint32_t dg = d32[j] >> 20;            // 12-bit digit
            uint32_t w  = dg >> 1;                 // packed word (logical)
            atomicAdd(&hist[w + (w >> 5)], 1u << ((dg & 1u) << 4));
        }
    }
    __syncthreads();

    // ---- wave scan: lane L owns logical words 32L..32L+31 (bins 64L..64L+63) ----
    uint32_t w[32];
    #pragma unroll
    for (int i = 0; i < 32; ++i) w[i] = hist[33 * L + i];  // b32, bank (L+i)%32: clean
    uint32_t run = 0;
    #pragma unroll
    for (int i = 0; i < 32; ++i) run += (w[i] & 0xFFFFu) + (w[i] >> 16);
    uint32_t v = run;
    #pragma unroll
    for (int d = 1; d < 64; d <<= 1) {
        uint32_t n = __shfl_up(v, (unsigned)d, 64);
        if (L >= d) v += n;
    }
    const uint32_t thrOff = v - run;   // exclusive prefix of this lane's bins

    // ---- gated bin-find for the 4 ranks ----
    {
        const uint32_t Ks[KSB] = {64u, 128u, 256u, 512u};
        #pragma unroll
        for (int s = 0; s < KSB; ++s) {
            uint32_t r = Ks[s] - 1u;
            if (r >= thrOff && r < thrOff + run) {     // exactly one lane
                uint32_t acc = thrOff;
                #pragma unroll
                for (int i = 0; i < 32; ++i) {
                    uint32_t c0 = w[i] & 0xFFFFu, c1 = w[i] >> 16;
                    if (r >= acc && r < acc + c0) selScr[s] = ((64u*L + 2u*i) << 12) | (r - acc);
                    acc += c0;
                    if (r >= acc && r < acc + c1) selScr[s] = ((64u*L + 2u*i + 1u) << 12) | (r - acc);
                    acc += c1;
                }
            }
        }
    }
    __syncthreads();

    // ---- collect threshold-bin members (hist now dead -> cand alias OK) ----
    const uint32_t b0 = selScr[0] >> 12, b1 = selScr[1] >> 12,
                   b2 = selScr[2] >> 12, b3 = selScr[3] >> 12;
    #pragma unroll
    for (int c = 0; c < NCHUNK; ++c) {
        uint4 kc = *(uint4*)&keyCache[256 * c + 4 * L];
        uint32_t d32[4] = {kc.x, kc.y, kc.z, kc.w};
        #pragma unroll
        for (int j = 0; j < 4; ++j) {
            uint32_t dg  = d32[j] >> 20;
            uint32_t p31 = ((d32[j] & 0xFFFFFu) << 11) | (uint32_t)(256 * c + 4 * L + j);
            if (dg == b0) { uint32_t p = atomicAdd(&selCnt[0], 1u); if (p < CAP) cand[0][p] = p31; }
            if (dg == b1) { uint32_t p = atomicAdd(&selCnt[1], 1u); if (p < CAP) cand[1][p] = p31; }
            if (dg == b2) { uint32_t p = atomicAdd(&selCnt[2], 1u); if (p < CAP) cand[2][p] = p31; }
            if (dg == b3) { uint32_t p = atomicAdd(&selCnt[3], 1u); if (p < CAP) cand[3][p] = p31; }
        }
    }
    __syncthreads();

    // ---- all-pairs rank within each tiny bin (C ~ 10-60) ----
    #pragma unroll
    for (int s = 0; s < KSB; ++s) {
        const uint32_t C = min(selCnt[s], (uint32_t)CAP);
        const uint32_t r = selScr[s] & 0xFFFu;
        for (uint32_t i = L; i < C; i += 64) {
            uint32_t ci = cand[s][i];
            uint32_t cnt = 0;
            for (uint32_t j = 0; j < C; ++j) cnt += (cand[s][j] < ci);  // broadcast reads
            if (cnt == r) selThr[s] = ci;    // unique keys -> one writer
        }
    }
    __syncthreads();

    // ---- masks: key <= T_s; key = (desc32<<11)|idx = (digit<<31)|packed31 ----
    const unsigned long long T0 = (((unsigned long long)b0) << 31) | selThr[0];
    const unsigned long long T1 = (((unsigned long long)b1) << 31) | selThr[1];
    const unsigned long long T2 = (((unsigned long long)b2) << 31) | selThr[2];
    const unsigned long long T3 = (((unsigned long long)b3) << 31) | selThr[3];
    float* outrow = out + (size_t)row * (KSB * F_DIM);
    #pragma unroll
    for (int c = 0; c < NCHUNK; ++c) {
        uint4 kc = *(uint4*)&keyCache[256 * c + 4 * L];
        uint32_t d32[4] = {kc.x, kc.y, kc.z, kc.w};
        f32x4 m0, m1, m2, m3;
        #pragma unroll
        for (int j = 0; j < 4; ++j) {
            unsigned long long k = (((unsigned long long)d32[j]) << 11) |
                                   (unsigned long long)(uint32_t)(256 * c + 4 * L + j);
            m0[j] = (k <= T0) ? 1.0f : 0.0f;
            m1[j] = (k <= T1) ? 1.0f : 0.0f;
            m2[j] = (k <= T2) ? 1.0f : 0.0f;
            m3[j] = (k <= T3) ? 1.0f : 0.0f;
        }
        const int off = 256 * c + 4 * L;
        __builtin_nontemporal_store(m0, (f32x4*)(outrow + 0 * F_DIM + off));
        __builtin_nontemporal_store(m1, (f32x4*)(outrow + 1 * F_DIM + off));
        __builtin_nontemporal_store(m2, (f32x4*)(outrow + 2 * F_DIM + off));
        __builtin_nontemporal_store(m3, (f32x4*)(outrow + 3 * F_DIM + off));
    }
}

extern "C" void kernel_launch(void* const* d_in, const int* in_sizes, int n_in,
                              void* d_out, int out_size, void* d_ws, size_t ws_size,
                              hipStream_t stream) {
    const float* scores = (const float*)d_in[0];
    const float* u      = (const float*)d_in[1];
    float* out          = (float*)d_out;
    const int rows = in_sizes[0] / F_DIM;  // 4096
    hsb_kernel<<<dim3(rows), dim3(64), 0, stream>>>(scores, u, out);
}

// Round 8
// 192.019 us; speedup vs baseline: 1.1215x; 1.1215x over previous
//
#include <hip/hip_runtime.h>
#include <stdint.h>

// B=128, K_fc=32 -> 4096 rows, F=2048, K_LIST={64,128,256,512}, TAU=1, EPS=1e-20.
// Output = M_hard exactly (straight-through term is numerically zero forward).
//
// R8: wave-per-row (R7 structure, zero real barriers) with the occupancy fix:
// keys stay in VGPRs (no 8 KB keyCache), LDS = padded 12-bit packed-u16
// histogram only (8.45 KB) -> LDS cap 18 blocks/CU; __launch_bounds__(64,4)
// caps VGPRs at 128 -> 16 waves/CU (vs R7's 9). Free-running waves mix
// load/logf/select/store phases across the CU; no barrier convoy.

#define F_DIM  2048
#define KSB    4
#define CAP    512
#define NCHUNK 8     // 8 chunks x 64 lanes x 4 elems = 2048

typedef float f32x4 __attribute__((ext_vector_type(4)));

// Monotonic descending key: kd(a) < kd(b)  <=>  a > b (total order on f32)
__device__ __forceinline__ uint32_t f32_desc_key(float x) {
    uint32_t u = __float_as_uint(x);
    uint32_t ka = (u & 0x80000000u) ? ~u : (u | 0x80000000u);
    return ~ka;
}

__global__ __launch_bounds__(64, 4)
void hsb_kernel(const float* __restrict__ scores,
                const float* __restrict__ uin,
                float* __restrict__ out) {
    const int row = blockIdx.x;
    const int L   = threadIdx.x;          // lane 0..63 (one wave per block)

    __shared__ uint32_t hist[2112];       // 4096 u16 bins packed + 1 pad word/32
    uint32_t (*cand)[CAP] = (uint32_t (*)[CAP])hist;  // alias: hist dead after find
    __shared__ uint32_t selScr[KSB];      // (bin<<12) | rem
    __shared__ uint32_t selCnt[KSB];
    __shared__ uint32_t selThr[KSB];      // packed31 threshold within bin

    const float4* s4 = (const float4*)(scores + row * F_DIM);
    const float4* u4 = (const float4*)(uin    + row * F_DIM);

    // ---- issue global loads; zero hist while they fly ----
    float4 sv[NCHUNK], uv[NCHUNK];
    #pragma unroll
    for (int c = 0; c < NCHUNK; ++c) { sv[c] = s4[64 * c + L]; uv[c] = u4[64 * c + L]; }
    {
        uint4 z = {0u, 0u, 0u, 0u};
        #pragma unroll
        for (int i = 0; i < 8; ++i) ((uint4*)hist)[64 * i + L] = z;   // 2048 words
        if (L < 16) ((uint4*)hist)[512 + L] = z;                      // pad tail
    }
    if (L < KSB) selCnt[L] = 0;
    __syncthreads();   // single-wave workgroup: folds to waitcnt

    // ---- keys (VGPR-resident) + 12-bit histogram ----
    uint32_t d32[4 * NCHUNK];
    #pragma unroll
    for (int c = 0; c < NCHUNK; ++c) {
        float ss[4] = {sv[c].x, sv[c].y, sv[c].z, sv[c].w};
        float uu[4] = {uv[c].x, uv[c].y, uv[c].z, uv[c].w};
        #pragma unroll
        for (int j = 0; j < 4; ++j) {
            float inner = -logf(uu[j] + 1e-20f);   // byte-identical reference math
            float g     = -logf(inner + 1e-20f);
            uint32_t k  = f32_desc_key(ss[j] + g);
            d32[4 * c + j] = k;
            uint32_t dg = k >> 20;                 // 12-bit digit
            uint32_t w  = dg >> 1;                 // packed word (logical)
            atomicAdd(&hist[w + (w >> 5)], 1u << ((dg & 1u) << 4));
        }
    }
    __syncthreads();

    // ---- wave scan: lane L owns logical words 32L..32L+31 (bins 64L..64L+63) ----
    uint32_t w[32];
    #pragma unroll
    for (int i = 0; i < 32; ++i) w[i] = hist[33 * L + i];  // bank (L+i)%32: 2-way, free
    uint32_t run = 0;
    #pragma unroll
    for (int i = 0; i < 32; ++i) run += (w[i] & 0xFFFFu) + (w[i] >> 16);
    uint32_t v = run;
    #pragma unroll
    for (int d = 1; d < 64; d <<= 1) {
        uint32_t n = __shfl_up(v, (unsigned)d, 64);
        if (L >= d) v += n;
    }
    const uint32_t thrOff = v - run;   // exclusive prefix of this lane's bins

    // ---- gated bin-find for the 4 ranks ----
    {
        const uint32_t Ks[KSB] = {64u, 128u, 256u, 512u};
        #pragma unroll
        for (int s = 0; s < KSB; ++s) {
            uint32_t r = Ks[s] - 1u;
            if (r >= thrOff && r < thrOff + run) {     // exactly one lane
                uint32_t acc = thrOff;
                #pragma unroll
                for (int i = 0; i < 32; ++i) {
                    uint32_t c0 = w[i] & 0xFFFFu, c1 = w[i] >> 16;
                    if (r >= acc && r < acc + c0) selScr[s] = ((64u*L + 2u*i) << 12) | (r - acc);
                    acc += c0;
                    if (r >= acc && r < acc + c1) selScr[s] = ((64u*L + 2u*i + 1u) << 12) | (r - acc);
                    acc += c1;
                }
            }
        }
    }
    __syncthreads();

    // ---- collect threshold-bin members (hist dead -> cand alias OK) ----
    const uint32_t b0 = selScr[0] >> 12, b1 = selScr[1] >> 12,
                   b2 = selScr[2] >> 12, b3 = selScr[3] >> 12;
    #pragma unroll
    for (int c = 0; c < NCHUNK; ++c) {
        #pragma unroll
        for (int j = 0; j < 4; ++j) {
            uint32_t k   = d32[4 * c + j];
            uint32_t dg  = k >> 20;
            uint32_t p31 = ((k & 0xFFFFFu) << 11) | (uint32_t)(256 * c + 4 * L + j);
            if (dg == b0) { uint32_t p = atomicAdd(&selCnt[0], 1u); if (p < CAP) cand[0][p] = p31; }
            if (dg == b1) { uint32_t p = atomicAdd(&selCnt[1], 1u); if (p < CAP) cand[1][p] = p31; }
            if (dg == b2) { uint32_t p = atomicAdd(&selCnt[2], 1u); if (p < CAP) cand[2][p] = p31; }
            if (dg == b3) { uint32_t p = atomicAdd(&selCnt[3], 1u); if (p < CAP) cand[3][p] = p31; }
        }
    }
    __syncthreads();

    // ---- all-pairs rank within each tiny bin (C ~ 30-60) ----
    #pragma unroll
    for (int s = 0; s < KSB; ++s) {
        const uint32_t C = min(selCnt[s], (uint32_t)CAP);
        const uint32_t r = selScr[s] & 0xFFFu;
        for (uint32_t i = L; i < C; i += 64) {
            uint32_t ci = cand[s][i];
            uint32_t cnt = 0;
            for (uint32_t j = 0; j < C; ++j) cnt += (cand[s][j] < ci);  // broadcast reads
            if (cnt == r) selThr[s] = ci;    // unique keys -> one writer
        }
    }
    __syncthreads();

    // ---- masks: key = (d32<<11)|idx = (digit<<31)|packed31; key <= T_s ----
    const unsigned long long T0 = (((unsigned long long)b0) << 31) | selThr[0];
    const unsigned long long T1 = (((unsigned long long)b1) << 31) | selThr[1];
    const unsigned long long T2 = (((unsigned long long)b2) << 31) | selThr[2];
    const unsigned long long T3 = (((unsigned long long)b3) << 31) | selThr[3];
    float* outrow = out + (size_t)row * (KSB * F_DIM);
    #pragma unroll
    for (int c = 0; c < NCHUNK; ++c) {
        f32x4 m0, m1, m2, m3;
        #pragma unroll
        for (int j = 0; j < 4; ++j) {
            unsigned long long k = (((unsigned long long)d32[4 * c + j]) << 11) |
                                   (unsigned long long)(uint32_t)(256 * c + 4 * L + j);
            m0[j] = (k <= T0) ? 1.0f : 0.0f;
            m1[j] = (k <= T1) ? 1.0f : 0.0f;
            m2[j] = (k <= T2) ? 1.0f : 0.0f;
            m3[j] = (k <= T3) ? 1.0f : 0.0f;
        }
        const int off = 256 * c + 4 * L;
        __builtin_nontemporal_store(m0, (f32x4*)(outrow + 0 * F_DIM + off));
        __builtin_nontemporal_store(m1, (f32x4*)(outrow + 1 * F_DIM + off));
        __builtin_nontemporal_store(m2, (f32x4*)(outrow + 2 * F_DIM + off));
        __builtin_nontemporal_store(m3, (f32x4*)(outrow + 3 * F_DIM + off));
    }
}

extern "C" void kernel_launch(void* const* d_in, const int* in_sizes, int n_in,
                              void* d_out, int out_size, void* d_ws, size_t ws_size,
                              hipStream_t stream) {
    const float* scores = (const float*)d_in[0];
    const float* u      = (const float*)d_in[1];
    float* out          = (float*)d_out;
    const int rows = in_sizes[0] / F_DIM;  // 4096
    hsb_kernel<<<dim3(rows), dim3(64), 0, stream>>>(scores, u, out);
}